// Round 1
// baseline (14082.686 us; speedup 1.0000x reference)
//
#include <hip/hip_runtime.h>
#include <math.h>

#define TT   256
#define BB   1024
#define YDIM 32
#define HDIM 1024
#define RDIM 512

typedef __attribute__((ext_vector_type(8))) short frag8;
typedef __attribute__((ext_vector_type(4))) float f32x4;

// ---------------- workspace layout (bytes) ----------------
#define OFF_NLL   ((size_t)0)
#define OFF_HA    ((size_t)4096)
#define SZ_HBUF   ((size_t)BB*RDIM*4)              // one fp32 h buffer (2 MB)
#define OFF_HB    (OFF_HA + 2*SZ_HBUF)
#define SZ_DBUF   ((size_t)BB*HDIM*2)              // one bf16 d buffer (2 MB)
#define OFF_D1    (OFF_HB + 2*SZ_HBUF)
#define OFF_D2    (OFF_D1 + 2*SZ_DBUF)
#define OFF_WG0H  (OFF_D2 + 2*SZ_DBUF)
#define OFF_WG0I  (OFF_WG0H + (size_t)1536*RDIM*2)
#define OFF_WG1I  (OFF_WG0I + (size_t)1536*YDIM*2)
#define OFF_WG1H  (OFF_WG1I + (size_t)1536*RDIM*2)
#define OFF_WD1   (OFF_WG1H + (size_t)1536*RDIM*2)
#define OFF_WD2   (OFF_WD1 + (size_t)HDIM*RDIM*2)
#define OFF_WMS   (OFF_WD2 + (size_t)HDIM*HDIM*2)
#define OFF_BI0   (OFF_WMS + (size_t)64*HDIM*2)
#define OFF_BH0   (OFF_BI0 + 1536*4)
#define OFF_BI1   (OFF_BH0 + 1536*4)
#define OFF_BH1   (OFF_BI1 + 1536*4)

__device__ __forceinline__ short f2bf(float f) {
  union { float f; unsigned u; } v; v.f = f;
  unsigned r = (v.u + 0x7fffu + ((v.u >> 16) & 1u)) >> 16;
  return (short)r;
}
__device__ __forceinline__ void cvt8(const float* s, short* d) {
  float4 a = *(const float4*)s;
  float4 b = *(const float4*)(s + 4);
  frag8 v;
  v[0]=f2bf(a.x); v[1]=f2bf(a.y); v[2]=f2bf(a.z); v[3]=f2bf(a.w);
  v[4]=f2bf(b.x); v[5]=f2bf(b.y); v[6]=f2bf(b.z); v[7]=f2bf(b.w);
  *(frag8*)d = v;
}
// gate-interleaved row permutation: out-row n' = q*48 + g*16 + u  <->  src row g*512 + q*16 + u
__device__ __forceinline__ int permRow(int n) {
  int q = n / 48, r = n - 48 * q, g = r >> 4, u = r & 15;
  return g * 512 + q * 16 + u;
}
__device__ __forceinline__ float sigf(float x) { return 1.0f / (1.0f + expf(-x)); }

// ---------------- generic MFMA K-loop ----------------
// A: global row-major [*, lda] (fp32 if CVT else bf16-as-short). B: prepacked bf16 [nrowsB, K].
// Tile: M=128 rows (base m0) x nrowsB cols. Wave computes MF x NF 16x16 frags at (wm, wn).
// LDS tiles padded to 72 shorts/row (144 B: 16B-aligned, 2-way bank aliasing only).
template<int MF, int NF, bool CVT>
__device__ void kloop(const void* Aglob, int lda, const short* Bglob, int nrowsB, int K,
                      int m0, int wm, int wn, short* ldsA, short* ldsB,
                      f32x4 (*acc)[NF], int tid)
{
  const int l = tid & 63, u = l & 15, quad = l >> 4;
  for (int k0 = 0; k0 < K; k0 += 64) {
    const int wdt = (K - k0 >= 64) ? 64 : 32;   // K is a multiple of 32
    const int shf = (wdt == 64) ? 3 : 2;        // 16B segs per row
    __syncthreads();
    {
      const int totA = 128 << shf;
      for (int s = tid; s < totA; s += 256) {
        int row = s >> shf;
        int kk  = (s - (row << shf)) << 3;
        if (CVT) {
          const float* src = (const float*)Aglob + (size_t)(m0 + row) * lda + k0 + kk;
          cvt8(src, ldsA + row * 72 + kk);
        } else {
          const short* src = (const short*)Aglob + (size_t)(m0 + row) * lda + k0 + kk;
          *(int4*)(ldsA + row * 72 + kk) = *(const int4*)src;
        }
      }
      const int totB = nrowsB << shf;
      for (int s = tid; s < totB; s += 256) {
        int row = s >> shf;
        int kk  = (s - (row << shf)) << 3;
        *(int4*)(ldsB + row * 72 + kk) = *(const int4*)(Bglob + (size_t)row * K + k0 + kk);
      }
    }
    __syncthreads();
    for (int kk2 = 0; kk2 * 32 < wdt; ++kk2) {
      frag8 a[MF], b[NF];
#pragma unroll
      for (int i = 0; i < MF; ++i)
        a[i] = *(const frag8*)(ldsA + (wm + 16 * i + u) * 72 + kk2 * 32 + quad * 8);
#pragma unroll
      for (int f = 0; f < NF; ++f)
        b[f] = *(const frag8*)(ldsB + (wn + 16 * f + u) * 72 + kk2 * 32 + quad * 8);
#pragma unroll
      for (int i = 0; i < MF; ++i)
#pragma unroll
        for (int f = 0; f < NF; ++f)
          acc[i][f] = __builtin_amdgcn_mfma_f32_16x16x32_bf16(a[i], b[f], acc[i][f], 0, 0, 0);
    }
  }
}

// ---------------- GRU tile (both layers) ----------------
// Computes, for batch rows [mb*128,+128) and units [nb*32,+32):
// gi = x @ Wgi^T (+bi), gh = h @ Wgh^T (+bh), then torch GRUCell combine. fp32 state in/out.
__device__ void gru_tile(int mb, int nb,
                         const void* Ax, int ldx, int Kx, const short* Wgi,
                         const float* Ah, const short* Wgh,
                         const float* bi, const float* bh,
                         const float* hold, float* hout,
                         short* ldsA, short* ldsB, int tid)
{
  f32x4 zero = {0.f, 0.f, 0.f, 0.f};
  f32x4 gi[4][3], gh[4][3];
#pragma unroll
  for (int i = 0; i < 4; ++i)
#pragma unroll
    for (int f = 0; f < 3; ++f) { gi[i][f] = zero; gh[i][f] = zero; }
  const int w = tid >> 6, l = tid & 63, u = l & 15, quad = l >> 4;
  const int wm = (w & 1) * 64, wn = (w >> 1) * 48;
  kloop<4, 3, true>(Ax, ldx, Wgi, 96, Kx, mb * 128, wm, wn, ldsA, ldsB, gi, tid);
  kloop<4, 3, true>(Ah, RDIM, Wgh, 96, RDIM, mb * 128, wm, wn, ldsA, ldsB, gh, tid);
  const int np = nb * 96 + (w >> 1) * 48 + u;     // permuted row of the r-gate
  const float bir = bi[np], biz = bi[np + 16], bin = bi[np + 32];
  const float bhr = bh[np], bhz = bh[np + 16], bhn = bh[np + 32];
  const int unit = nb * 32 + (w >> 1) * 16 + u;
#pragma unroll
  for (int i = 0; i < 4; ++i)
#pragma unroll
    for (int j = 0; j < 4; ++j) {
      int row = mb * 128 + wm + 16 * i + quad * 4 + j;
      float r = sigf((gi[i][0][j] + bir) + (gh[i][0][j] + bhr));
      float z = sigf((gi[i][1][j] + biz) + (gh[i][1][j] + bhz));
      float n = tanhf((gi[i][2][j] + bin) + r * (gh[i][2][j] + bhn));
      float ho = hold[(size_t)row * RDIM + unit];
      hout[(size_t)row * RDIM + unit] = (1.f - z) * n + z * ho;
    }
}

// ---------------- decoder Linear+ReLU tile (128x128) ----------------
template<bool CVT>
__device__ void dec_tile(int mb, int nb, const void* A, int lda, int K,
                         const short* W, const float* bias, short* outp,
                         short* ldsA, short* ldsB, int tid)
{
  f32x4 zero = {0.f, 0.f, 0.f, 0.f};
  f32x4 acc[4][4];
#pragma unroll
  for (int i = 0; i < 4; ++i)
#pragma unroll
    for (int f = 0; f < 4; ++f) acc[i][f] = zero;
  const int w = tid >> 6, l = tid & 63, u = l & 15, quad = l >> 4;
  const int wm = (w & 1) * 64, wn = (w >> 1) * 64;
  kloop<4, 4, CVT>(A, lda, W, 128, K, mb * 128, wm, wn, ldsA, ldsB, acc, tid);
  const int colb = nb * 128 + wn + u;
  float bv[4];
#pragma unroll
  for (int f = 0; f < 4; ++f) bv[f] = bias[colb + 16 * f];
#pragma unroll
  for (int i = 0; i < 4; ++i)
#pragma unroll
    for (int f = 0; f < 4; ++f)
#pragma unroll
      for (int j = 0; j < 4; ++j) {
        int row = mb * 128 + wm + 16 * i + quad * 4 + j;
        float v = acc[i][f][j] + bv[f];
        if (v < 0.f) v = 0.f;
        outp[(size_t)row * HDIM + colb + 16 * f] = f2bf(v);
      }
}

// ---------------- mean/std + gaussian NLL tile (128 rows, all 32 y-dims) ----------------
__device__ void ms_tile(int mb, int tstep, const short* d2p, const short* Wms,
                        const float* mbias, const float* sbias, const float* y,
                        float* nll, short* ldsA, short* ldsB, int tid)
{
  f32x4 zero = {0.f, 0.f, 0.f, 0.f};
  f32x4 acc[2][4];
#pragma unroll
  for (int i = 0; i < 2; ++i)
#pragma unroll
    for (int f = 0; f < 4; ++f) acc[i][f] = zero;
  const int w = tid >> 6, l = tid & 63, u = l & 15, quad = l >> 4;
  kloop<2, 4, false>(d2p, HDIM, Wms, 64, HDIM, mb * 128, w * 32, 0, ldsA, ldsB, acc, tid);
  float lsum = 0.f;
#pragma unroll
  for (int i = 0; i < 2; ++i)
#pragma unroll
    for (int j = 0; j < 4; ++j) {
      int row = mb * 128 + w * 32 + 16 * i + quad * 4 + j;
      const float* yr = y + ((size_t)tstep * BB + row) * YDIM;
#pragma unroll
      for (int f = 0; f < 2; ++f) {
        int c = 16 * f + u;
        float m  = acc[i][f][j] + mbias[c];
        float sp = acc[i][f + 2][j] + sbias[c];
        float sg = (sp > 20.f) ? sp : log1pf(expf(sp));
        float dv = (yr[c] - m) / sg;
        lsum += dv * dv + 2.f * logf(sg) + 1.8378770664093453f;  // + log(2*pi)
      }
    }
  lsum *= 0.5f;
#pragma unroll
  for (int o = 32; o; o >>= 1) lsum += __shfl_xor(lsum, o);
  if (l == 0) atomicAdd(nll, lsum);
}

// ---------------- prepack: bf16 weight repack (+gate interleave), zero state ----------------
__global__ __launch_bounds__(256) void prepack_kernel(
    const float* dw1, const float* dw2,
    const float* mw, const float* sw,
    const float* wih0, const float* whh0, const float* bih0, const float* bhh0,
    const float* wih1, const float* whh1, const float* bih1, const float* bhh1,
    char* __restrict__ ws)
{
  const size_t g = (size_t)blockIdx.x * 256 + threadIdx.x;
  const size_t N = (size_t)gridDim.x * 256;
  // zero hA[2], hB[2] (fp32)
  float4 z4 = {0.f, 0.f, 0.f, 0.f};
  float4* hz = (float4*)(ws + OFF_HA);
  for (size_t i = g; i < (size_t)4 * BB * RDIM / 4; i += N) hz[i] = z4;
  if (g == 0) *(float*)(ws + OFF_NLL) = 0.f;

  short* Wg0h = (short*)(ws + OFF_WG0H);
  short* Wg0i = (short*)(ws + OFF_WG0I);
  short* Wg1i = (short*)(ws + OFF_WG1I);
  short* Wg1h = (short*)(ws + OFF_WG1H);
  short* Wd1  = (short*)(ws + OFF_WD1);
  short* Wd2  = (short*)(ws + OFF_WD2);
  short* Wms  = (short*)(ws + OFF_WMS);
  float* bi0  = (float*)(ws + OFF_BI0);
  float* bh0  = (float*)(ws + OFF_BH0);
  float* bi1  = (float*)(ws + OFF_BI1);
  float* bh1  = (float*)(ws + OFF_BH1);

  for (size_t s = g; s < (size_t)1536 * RDIM / 8; s += N) {
    int row = (int)(s >> 6), seg = (int)(s & 63) << 3;
    int pr = permRow(row);
    cvt8(whh0 + (size_t)pr * RDIM + seg, Wg0h + (size_t)row * RDIM + seg);
    cvt8(wih1 + (size_t)pr * RDIM + seg, Wg1i + (size_t)row * RDIM + seg);
    cvt8(whh1 + (size_t)pr * RDIM + seg, Wg1h + (size_t)row * RDIM + seg);
  }
  for (size_t s = g; s < (size_t)1536 * YDIM / 8; s += N) {
    int row = (int)(s >> 2), seg = (int)(s & 3) << 3;
    cvt8(wih0 + (size_t)permRow(row) * YDIM + seg, Wg0i + (size_t)row * YDIM + seg);
  }
  for (size_t s = g; s < (size_t)HDIM * RDIM / 8; s += N)
    cvt8(dw1 + s * 8, Wd1 + s * 8);
  for (size_t s = g; s < (size_t)HDIM * HDIM / 8; s += N)
    cvt8(dw2 + s * 8, Wd2 + s * 8);
  for (size_t s = g; s < (size_t)64 * HDIM / 8; s += N) {
    int row = (int)(s >> 7), seg = (int)(s & 127) << 3;
    const float* src = (row < 32) ? (mw + (size_t)row * HDIM + seg)
                                  : (sw + (size_t)(row - 32) * HDIM + seg);
    cvt8(src, Wms + (size_t)row * HDIM + seg);
  }
  for (size_t s = g; s < 1536; s += N) {
    int pr = permRow((int)s);
    bi0[s] = bih0[pr]; bh0[s] = bhh0[pr];
    bi1[s] = bih1[pr]; bh1[s] = bhh1[pr];
  }
}

// ---------------- one pipeline phase ----------------
// phase p (0..258):
//  t in [0,128)    : GRU1  -> h1_{p-1}           (active 1<=p<=255)
//  t in [128,192)  : D2    -> d2 for step p-2    (active 2<=p<=257)
//  t in [192,200)  : MS    -> nll for step p-3   (active 3<=p<=258)
//  t in [200,328)  : GRU0  -> h_l0_p             (active p<=255)
//  t in [328,392)  : D1    -> d1 for step p-1    (active 1<=p<=256)
__global__ __launch_bounds__(256, 2) void phase_kernel(
    int p, const float* __restrict__ y,
    const float* db1, const float* db2, const float* mbias, const float* sbias,
    char* __restrict__ ws)
{
  __shared__ short ldsA[128 * 72];
  __shared__ short ldsB[128 * 72];
  const int tid = threadIdx.x;
  const int t = blockIdx.x;
  const int cur = p & 1, prv = cur ^ 1;

  float* hA0 = (float*)(ws + OFF_HA);
  float* hB0 = (float*)(ws + OFF_HB);
  short* d10 = (short*)(ws + OFF_D1);
  short* d20 = (short*)(ws + OFF_D2);
  float* hAc = hA0 + (size_t)cur * BB * RDIM;
  float* hAp = hA0 + (size_t)prv * BB * RDIM;
  float* hBc = hB0 + (size_t)cur * BB * RDIM;
  float* hBp = hB0 + (size_t)prv * BB * RDIM;
  short* d1c = d10 + (size_t)cur * BB * HDIM;
  short* d1p = d10 + (size_t)prv * BB * HDIM;
  short* d2c = d20 + (size_t)cur * BB * HDIM;
  short* d2p = d20 + (size_t)prv * BB * HDIM;
  const short* Wg0h = (const short*)(ws + OFF_WG0H);
  const short* Wg0i = (const short*)(ws + OFF_WG0I);
  const short* Wg1i = (const short*)(ws + OFF_WG1I);
  const short* Wg1h = (const short*)(ws + OFF_WG1H);
  const short* Wd1  = (const short*)(ws + OFF_WD1);
  const short* Wd2  = (const short*)(ws + OFF_WD2);
  const short* Wms  = (const short*)(ws + OFF_WMS);
  const float* bi0  = (const float*)(ws + OFF_BI0);
  const float* bh0  = (const float*)(ws + OFF_BH0);
  const float* bi1  = (const float*)(ws + OFF_BI1);
  const float* bh1  = (const float*)(ws + OFF_BH1);
  float* nllp = (float*)(ws + OFF_NLL);

  if (t < 128) {
    if (p >= 1 && p <= 255) {
      int mb = t >> 4, nb = t & 15;
      gru_tile(mb, nb, hAp, RDIM, RDIM, Wg1i + (size_t)nb * 96 * RDIM,
               hBp, Wg1h + (size_t)nb * 96 * RDIM,
               bi1, bh1, hBp, hBc, ldsA, ldsB, tid);
    }
  } else if (t < 192) {
    if (p >= 2 && p <= 257) {
      int q = t - 128, mb = q >> 3, nb = q & 7;
      dec_tile<false>(mb, nb, d1p, HDIM, HDIM, Wd2 + (size_t)nb * 128 * HDIM,
                      db2, d2c, ldsA, ldsB, tid);
    }
  } else if (t < 200) {
    if (p >= 3 && p <= 258) {
      ms_tile(t - 192, p - 3, d2p, Wms, mbias, sbias, y, nllp, ldsA, ldsB, tid);
    }
  } else if (t < 328) {
    if (p <= 255) {
      int q = t - 200, mb = q >> 4, nb = q & 15;
      gru_tile(mb, nb, y + (size_t)p * BB * YDIM, YDIM, YDIM,
               Wg0i + (size_t)nb * 96 * YDIM,
               hAp, Wg0h + (size_t)nb * 96 * RDIM,
               bi0, bh0, hAp, hAc, ldsA, ldsB, tid);
    }
  } else {
    if (p >= 1 && p <= 256) {
      int q = t - 328, mb = q >> 3, nb = q & 7;
      dec_tile<true>(mb, nb, hBp, RDIM, RDIM, Wd1 + (size_t)nb * 128 * RDIM,
                     db1, d1c, ldsA, ldsB, tid);
    }
  }
}

__global__ void finish_kernel(float* out, const char* ws)
{
  if (threadIdx.x == 0 && blockIdx.x == 0)
    out[0] = *(const float*)(ws + OFF_NLL);
}

extern "C" void kernel_launch(void* const* d_in, const int* in_sizes, int n_in,
                              void* d_out, int out_size, void* d_ws, size_t ws_size,
                              hipStream_t stream) {
  (void)in_sizes; (void)n_in; (void)out_size; (void)ws_size;
  const float* y    = (const float*)d_in[0];
  const float* dw1  = (const float*)d_in[1];
  const float* db1  = (const float*)d_in[2];
  const float* dw2  = (const float*)d_in[3];
  const float* db2  = (const float*)d_in[4];
  const float* mw   = (const float*)d_in[5];
  const float* mbias= (const float*)d_in[6];
  const float* sw   = (const float*)d_in[7];
  const float* sbias= (const float*)d_in[8];
  const float* wih0 = (const float*)d_in[9];
  const float* whh0 = (const float*)d_in[10];
  const float* bih0 = (const float*)d_in[11];
  const float* bhh0 = (const float*)d_in[12];
  const float* wih1 = (const float*)d_in[13];
  const float* whh1 = (const float*)d_in[14];
  const float* bih1 = (const float*)d_in[15];
  const float* bhh1 = (const float*)d_in[16];
  char* ws = (char*)d_ws;
  float* out = (float*)d_out;

  prepack_kernel<<<256, 256, 0, stream>>>(dw1, dw2, mw, sw,
                                          wih0, whh0, bih0, bhh0,
                                          wih1, whh1, bih1, bhh1, ws);
  for (int p = 0; p < 259; ++p)
    phase_kernel<<<392, 256, 0, stream>>>(p, y, db1, db2, mbias, sbias, ws);
  finish_kernel<<<1, 1, 0, stream>>>(out, ws);
}

// Round 2
// 5803.611 us; speedup vs baseline: 2.4265x; 2.4265x over previous
//
#include <hip/hip_runtime.h>
#include <math.h>

#define TT   256
#define BB   1024
#define YDIM 32
#define HDIM 1024
#define RDIM 512

typedef __attribute__((ext_vector_type(8))) short frag8;
typedef __attribute__((ext_vector_type(4))) float f32x4;

#define LDS_BUF 16384  // shorts per double-buffer half: (128 A rows + 128 B rows) x 64

// ---------------- workspace layout (bytes) ----------------
#define OFF_NLL   ((size_t)0)
#define OFF_HAF   ((size_t)4096)                     // fp32 h0 x2 (state)
#define SZ_HF     ((size_t)BB*RDIM*4)
#define OFF_HBF   (OFF_HAF + 2*SZ_HF)                // fp32 h1 x2
#define OFF_HA16  (OFF_HBF + 2*SZ_HF)                // bf16 h0 x2 (GEMM operand copy)
#define SZ_H16    ((size_t)BB*RDIM*2)
#define OFF_HB16  (OFF_HA16 + 2*SZ_H16)              // bf16 h1 x2
#define OFF_D1    (OFF_HB16 + 2*SZ_H16)              // bf16 d1 x2
#define SZ_DBUF   ((size_t)BB*HDIM*2)
#define OFF_D2    (OFF_D1 + 2*SZ_DBUF)               // bf16 d2 x2
#define OFF_Y16   (OFF_D2 + 2*SZ_DBUF)               // bf16 y [T,B,32]
#define OFF_WG0I  (OFF_Y16 + (size_t)TT*BB*YDIM*2)
#define OFF_WG0H  (OFF_WG0I + (size_t)1536*YDIM*2)
#define OFF_WG1I  (OFF_WG0H + (size_t)1536*RDIM*2)
#define OFF_WG1H  (OFF_WG1I + (size_t)1536*RDIM*2)
#define OFF_WD1   (OFF_WG1H + (size_t)1536*RDIM*2)
#define OFF_WD2   (OFF_WD1 + (size_t)HDIM*RDIM*2)
#define OFF_WMS   (OFF_WD2 + (size_t)HDIM*HDIM*2)
#define OFF_BI0   (OFF_WMS + (size_t)64*HDIM*2)
#define OFF_BH0   (OFF_BI0 + 1536*4)
#define OFF_BI1   (OFF_BH0 + 1536*4)
#define OFF_BH1   (OFF_BI1 + 1536*4)

__device__ __forceinline__ short f2bf(float f) {
  union { float f; unsigned u; } v; v.f = f;
  unsigned r = (v.u + 0x7fffu + ((v.u >> 16) & 1u)) >> 16;
  return (short)r;
}
__device__ __forceinline__ void cvt8(const float* s, short* d) {
  float4 a = *(const float4*)s;
  float4 b = *(const float4*)(s + 4);
  frag8 v;
  v[0]=f2bf(a.x); v[1]=f2bf(a.y); v[2]=f2bf(a.z); v[3]=f2bf(a.w);
  v[4]=f2bf(b.x); v[5]=f2bf(b.y); v[6]=f2bf(b.z); v[7]=f2bf(b.w);
  *(frag8*)d = v;
}
// gate-interleaved row permutation: packed row n = q*48 + g*16 + u  <->  src row g*512 + q*16 + u
__device__ __forceinline__ int permRow(int n) {
  int q = n / 48, r = n - 48 * q, g = r >> 4, u = r & 15;
  return g * 512 + q * 16 + u;
}
__device__ __forceinline__ float sigf(float x) { return 1.0f / (1.0f + expf(-x)); }

// async 16B global -> LDS (dest = uniform base + lane*16)
__device__ __forceinline__ void gload16(const short* g, short* l) {
  __builtin_amdgcn_global_load_lds(
      (const __attribute__((address_space(1))) void*)g,
      (__attribute__((address_space(3))) void*)l, 16, 0, 0);
}

// ---------------- double-buffered MFMA K-loop, 64-wide chunks ----------------
// A: bf16 [*, lda], 128 rows from m0. B: prepacked bf16 [nrowsB, ldb].
// LDS tile layout: 16B unit p = row*8 + (q ^ (row&7)), q = logical 8-elem segment.
template<int MF, int NF>
__device__ __forceinline__ void kloop64(
    const short* __restrict__ A, int lda, int m0,
    const short* __restrict__ B, int ldb, int nrowsB, int K,
    int wm, int wn, short* lds, f32x4 (*acc)[NF], int tid)
{
  const int l = tid & 63, w = tid >> 6, u = l & 15, quad = l >> 4;
  const int nk = K >> 6;
  const int bunits = nrowsB << 3;

  auto stage = [&](int kc, int buf) {
    short* base = lds + buf * LDS_BUF;
    const int k0 = kc << 6;
    for (int c = (w << 6); c < 1024; c += 256) {
      int p = c + l, r = p >> 3, q = (p & 7) ^ (r & 7);
      gload16(A + (size_t)(m0 + r) * lda + k0 + (q << 3), base + (c << 3));
    }
    short* bb = base + 8192;
    for (int c = (w << 6); c < bunits; c += 256) {
      int p = c + l, r = p >> 3, q = (p & 7) ^ (r & 7);
      gload16(B + (size_t)r * ldb + k0 + (q << 3), bb + (c << 3));
    }
  };

  stage(0, 0);
  __syncthreads();
  for (int kc = 0; kc < nk; ++kc) {
    if (kc + 1 < nk) stage(kc + 1, (kc + 1) & 1);   // overlaps compute below
    const short* base = lds + (kc & 1) * LDS_BUF;
#pragma unroll
    for (int kk2 = 0; kk2 < 2; ++kk2) {
      const int q = (kk2 << 2) + quad;
      const int aoff = (q ^ (u & 7)) << 3;
      frag8 a[MF], b[NF];
#pragma unroll
      for (int i = 0; i < MF; ++i)
        a[i] = *(const frag8*)(base + ((wm + (i << 4) + u) << 6) + aoff);
#pragma unroll
      for (int f = 0; f < NF; ++f)
        b[f] = *(const frag8*)(base + 8192 + ((wn + (f << 4) + u) << 6) + aoff);
#pragma unroll
      for (int i = 0; i < MF; ++i)
#pragma unroll
        for (int f = 0; f < NF; ++f)
          acc[i][f] = __builtin_amdgcn_mfma_f32_16x16x32_bf16(a[i], b[f], acc[i][f], 0, 0, 0);
    }
    __syncthreads();  // drains stage(kc+1) loads (vmcnt 0) + guards buffer reuse
  }
}

// single 32-wide chunk (GRU layer0 gi, K=32)
template<int MF, int NF>
__device__ __forceinline__ void kloop32(
    const short* __restrict__ A, int lda, int m0,
    const short* __restrict__ B, int nrowsB,
    int wm, int wn, short* lds, f32x4 (*acc)[NF], int tid)
{
  const int l = tid & 63, w = tid >> 6, u = l & 15, quad = l >> 4;
  short* base = lds;
  for (int c = (w << 6); c < 512; c += 256) {
    int p = c + l, r = p >> 2, q = (p & 3) ^ (r & 3);
    gload16(A + (size_t)(m0 + r) * lda + (q << 3), base + (c << 3));
  }
  short* bb = base + 4096;
  const int bunits = nrowsB << 2;
  for (int c = (w << 6); c < bunits; c += 256) {
    int p = c + l, r = p >> 2, q = (p & 3) ^ (r & 3);
    gload16(B + (size_t)r * 32 + (q << 3), bb + (c << 3));
  }
  __syncthreads();
  const int aoff = (quad ^ (u & 3)) << 3;
  frag8 a[MF], b[NF];
#pragma unroll
  for (int i = 0; i < MF; ++i)
    a[i] = *(const frag8*)(base + ((wm + (i << 4) + u) << 5) + aoff);
#pragma unroll
  for (int f = 0; f < NF; ++f)
    b[f] = *(const frag8*)(base + 4096 + ((wn + (f << 4) + u) << 5) + aoff);
#pragma unroll
  for (int i = 0; i < MF; ++i)
#pragma unroll
    for (int f = 0; f < NF; ++f)
      acc[i][f] = __builtin_amdgcn_mfma_f32_16x16x32_bf16(a[i], b[f], acc[i][f], 0, 0, 0);
  __syncthreads();
}

// ---------------- GRU tile ----------------
template<bool GI32>
__device__ void gru_tile(int mb, int nb,
                         const short* Ax, int ldx, const short* Wgi,
                         const short* Ah, const short* Wgh,
                         const float* bi, const float* bh,
                         const float* hold, float* hout, short* h16out,
                         short* lds, int tid)
{
  f32x4 zero = {0.f, 0.f, 0.f, 0.f};
  f32x4 gi[4][3], gh[4][3];
#pragma unroll
  for (int i = 0; i < 4; ++i)
#pragma unroll
    for (int f = 0; f < 3; ++f) { gi[i][f] = zero; gh[i][f] = zero; }
  const int w = tid >> 6, l = tid & 63, u = l & 15, quad = l >> 4;
  const int wm = (w & 1) * 64, wn = (w >> 1) * 48;
  if (GI32)
    kloop32<4, 3>(Ax, ldx, mb * 128, Wgi, 96, wm, wn, lds, gi, tid);
  else
    kloop64<4, 3>(Ax, ldx, mb * 128, Wgi, RDIM, 96, RDIM, wm, wn, lds, gi, tid);
  kloop64<4, 3>(Ah, RDIM, mb * 128, Wgh, RDIM, 96, RDIM, wm, wn, lds, gh, tid);

  const int np = nb * 96 + (w >> 1) * 48 + u;
  const float bir = bi[np], biz = bi[np + 16], bin = bi[np + 32];
  const float bhr = bh[np], bhz = bh[np + 16], bhn = bh[np + 32];
  const int unit = nb * 32 + (w >> 1) * 16 + u;
#pragma unroll
  for (int i = 0; i < 4; ++i)
#pragma unroll
    for (int j = 0; j < 4; ++j) {
      int row = mb * 128 + wm + 16 * i + quad * 4 + j;
      float r = sigf((gi[i][0][j] + bir) + (gh[i][0][j] + bhr));
      float z = sigf((gi[i][1][j] + biz) + (gh[i][1][j] + bhz));
      float n = tanhf((gi[i][2][j] + bin) + r * (gh[i][2][j] + bhn));
      float ho = hold[(size_t)row * RDIM + unit];
      float hn = (1.f - z) * n + z * ho;
      hout[(size_t)row * RDIM + unit] = hn;
      h16out[(size_t)row * RDIM + unit] = f2bf(hn);
    }
}

// ---------------- decoder Linear+ReLU tile (128x128) ----------------
__device__ void dec_tile(int mb, int nb, const short* A, int lda, int K,
                         const short* W, const float* bias, short* outp,
                         short* lds, int tid)
{
  f32x4 zero = {0.f, 0.f, 0.f, 0.f};
  f32x4 acc[4][4];
#pragma unroll
  for (int i = 0; i < 4; ++i)
#pragma unroll
    for (int f = 0; f < 4; ++f) acc[i][f] = zero;
  const int w = tid >> 6, l = tid & 63, u = l & 15, quad = l >> 4;
  const int wm = (w & 1) * 64, wn = (w >> 1) * 64;
  kloop64<4, 4>(A, lda, mb * 128, W, K, 128, K, wm, wn, lds, acc, tid);
  const int colb = nb * 128 + wn + u;
  float bv[4];
#pragma unroll
  for (int f = 0; f < 4; ++f) bv[f] = bias[colb + 16 * f];
#pragma unroll
  for (int i = 0; i < 4; ++i)
#pragma unroll
    for (int f = 0; f < 4; ++f)
#pragma unroll
      for (int j = 0; j < 4; ++j) {
        int row = mb * 128 + wm + 16 * i + quad * 4 + j;
        float v = acc[i][f][j] + bv[f];
        if (v < 0.f) v = 0.f;
        outp[(size_t)row * HDIM + colb + 16 * f] = f2bf(v);
      }
}

// ---------------- mean/std + gaussian NLL tile ----------------
__device__ void ms_tile(int mb, int tstep, const short* d2p, const short* Wms,
                        const float* mbias, const float* sbias, const float* y,
                        float* nll, short* lds, int tid)
{
  f32x4 zero = {0.f, 0.f, 0.f, 0.f};
  f32x4 acc[2][4];
#pragma unroll
  for (int i = 0; i < 2; ++i)
#pragma unroll
    for (int f = 0; f < 4; ++f) acc[i][f] = zero;
  const int w = tid >> 6, l = tid & 63, u = l & 15, quad = l >> 4;
  kloop64<2, 4>(d2p, HDIM, mb * 128, Wms, HDIM, 64, HDIM, w * 32, 0, lds, acc, tid);
  float lsum = 0.f;
#pragma unroll
  for (int i = 0; i < 2; ++i)
#pragma unroll
    for (int j = 0; j < 4; ++j) {
      int row = mb * 128 + w * 32 + 16 * i + quad * 4 + j;
      const float* yr = y + ((size_t)tstep * BB + row) * YDIM;
#pragma unroll
      for (int f = 0; f < 2; ++f) {
        int c = 16 * f + u;
        float m  = acc[i][f][j] + mbias[c];
        float sp = acc[i][f + 2][j] + sbias[c];
        float sg = (sp > 20.f) ? sp : log1pf(expf(sp));
        float dv = (yr[c] - m) / sg;
        lsum += dv * dv + 2.f * logf(sg) + 1.8378770664093453f;
      }
    }
  lsum *= 0.5f;
#pragma unroll
  for (int o = 32; o; o >>= 1) lsum += __shfl_xor(lsum, o);
  if (l == 0) atomicAdd(nll, lsum);
}

// ---------------- prepack ----------------
__global__ __launch_bounds__(256) void prepack_kernel(
    const float* y, const float* dw1, const float* dw2,
    const float* mw, const float* sw,
    const float* wih0, const float* whh0, const float* bih0, const float* bhh0,
    const float* wih1, const float* whh1, const float* bih1, const float* bhh1,
    char* __restrict__ ws)
{
  const size_t g = (size_t)blockIdx.x * 256 + threadIdx.x;
  const size_t N = (size_t)gridDim.x * 256;
  // zero fp32 h state (4 bufs) and bf16 h copies (4 bufs)
  float4 z4 = {0.f, 0.f, 0.f, 0.f};
  float4* hz = (float4*)(ws + OFF_HAF);
  for (size_t i = g; i < (size_t)4 * BB * RDIM / 4; i += N) hz[i] = z4;
  int4 zi = {0, 0, 0, 0};
  int4* h16z = (int4*)(ws + OFF_HA16);
  for (size_t i = g; i < (size_t)4 * BB * RDIM / 8; i += N) h16z[i] = zi;
  if (g == 0) *(float*)(ws + OFF_NLL) = 0.f;

  short* y16  = (short*)(ws + OFF_Y16);
  short* Wg0i = (short*)(ws + OFF_WG0I);
  short* Wg0h = (short*)(ws + OFF_WG0H);
  short* Wg1i = (short*)(ws + OFF_WG1I);
  short* Wg1h = (short*)(ws + OFF_WG1H);
  short* Wd1  = (short*)(ws + OFF_WD1);
  short* Wd2  = (short*)(ws + OFF_WD2);
  short* Wms  = (short*)(ws + OFF_WMS);
  float* bi0  = (float*)(ws + OFF_BI0);
  float* bh0  = (float*)(ws + OFF_BH0);
  float* bi1  = (float*)(ws + OFF_BI1);
  float* bh1  = (float*)(ws + OFF_BH1);

  for (size_t s = g; s < (size_t)TT * BB * YDIM / 8; s += N)
    cvt8(y + s * 8, y16 + s * 8);
  for (size_t s = g; s < (size_t)1536 * RDIM / 8; s += N) {
    int row = (int)(s >> 6), seg = (int)(s & 63) << 3;
    int pr = permRow(row);
    cvt8(whh0 + (size_t)pr * RDIM + seg, Wg0h + (size_t)row * RDIM + seg);
    cvt8(wih1 + (size_t)pr * RDIM + seg, Wg1i + (size_t)row * RDIM + seg);
    cvt8(whh1 + (size_t)pr * RDIM + seg, Wg1h + (size_t)row * RDIM + seg);
  }
  for (size_t s = g; s < (size_t)1536 * YDIM / 8; s += N) {
    int row = (int)(s >> 2), seg = (int)(s & 3) << 3;
    cvt8(wih0 + (size_t)permRow(row) * YDIM + seg, Wg0i + (size_t)row * YDIM + seg);
  }
  for (size_t s = g; s < (size_t)HDIM * RDIM / 8; s += N)
    cvt8(dw1 + s * 8, Wd1 + s * 8);
  for (size_t s = g; s < (size_t)HDIM * HDIM / 8; s += N)
    cvt8(dw2 + s * 8, Wd2 + s * 8);
  for (size_t s = g; s < (size_t)64 * HDIM / 8; s += N) {
    int row = (int)(s >> 7), seg = (int)(s & 127) << 3;
    const float* src = (row < 32) ? (mw + (size_t)row * HDIM + seg)
                                  : (sw + (size_t)(row - 32) * HDIM + seg);
    cvt8(src, Wms + (size_t)row * HDIM + seg);
  }
  for (size_t s = g; s < 1536; s += N) {
    int pr = permRow((int)s);
    bi0[s] = bih0[pr]; bh0[s] = bhh0[pr];
    bi1[s] = bih1[pr]; bh1[s] = bhh1[pr];
  }
}

// ---------------- one pipeline phase ----------------
__global__ __launch_bounds__(256, 2) void phase_kernel(
    int p, const float* __restrict__ y,
    const float* db1, const float* db2, const float* mbias, const float* sbias,
    char* __restrict__ ws)
{
  __shared__ short lds[2 * LDS_BUF];
  const int tid = threadIdx.x;
  const int t = blockIdx.x;
  const int cur = p & 1, prv = cur ^ 1;

  float* hAf = (float*)(ws + OFF_HAF);
  float* hBf = (float*)(ws + OFF_HBF);
  short* hA16 = (short*)(ws + OFF_HA16);
  short* hB16 = (short*)(ws + OFF_HB16);
  short* d10 = (short*)(ws + OFF_D1);
  short* d20 = (short*)(ws + OFF_D2);
  const short* y16 = (const short*)(ws + OFF_Y16);

  float* hAfc = hAf + (size_t)cur * BB * RDIM;
  float* hAfp = hAf + (size_t)prv * BB * RDIM;
  float* hBfc = hBf + (size_t)cur * BB * RDIM;
  float* hBfp = hBf + (size_t)prv * BB * RDIM;
  short* hA16c = hA16 + (size_t)cur * BB * RDIM;
  short* hA16p = hA16 + (size_t)prv * BB * RDIM;
  short* hB16c = hB16 + (size_t)cur * BB * RDIM;
  short* hB16p = hB16 + (size_t)prv * BB * RDIM;
  short* d1c = d10 + (size_t)cur * BB * HDIM;
  short* d1p = d10 + (size_t)prv * BB * HDIM;
  short* d2c = d20 + (size_t)cur * BB * HDIM;
  short* d2p = d20 + (size_t)prv * BB * HDIM;

  const short* Wg0i = (const short*)(ws + OFF_WG0I);
  const short* Wg0h = (const short*)(ws + OFF_WG0H);
  const short* Wg1i = (const short*)(ws + OFF_WG1I);
  const short* Wg1h = (const short*)(ws + OFF_WG1H);
  const short* Wd1  = (const short*)(ws + OFF_WD1);
  const short* Wd2  = (const short*)(ws + OFF_WD2);
  const short* Wms  = (const short*)(ws + OFF_WMS);
  const float* bi0  = (const float*)(ws + OFF_BI0);
  const float* bh0  = (const float*)(ws + OFF_BH0);
  const float* bi1  = (const float*)(ws + OFF_BI1);
  const float* bh1  = (const float*)(ws + OFF_BH1);
  float* nllp = (float*)(ws + OFF_NLL);

  if (t < 128) {                    // GRU1 -> h1_{p-1}
    if (p >= 1 && p <= 255) {
      int mb = t >> 4, nb = t & 15;
      gru_tile<false>(mb, nb,
                      hA16p, RDIM, Wg1i + (size_t)nb * 96 * RDIM,
                      hB16p, Wg1h + (size_t)nb * 96 * RDIM,
                      bi1, bh1, hBfp, hBfc, hB16c, lds, tid);
    }
  } else if (t < 192) {             // D2 for step p-2
    if (p >= 2 && p <= 257) {
      int q = t - 128, mb = q >> 3, nb = q & 7;
      dec_tile(mb, nb, d1p, HDIM, HDIM, Wd2 + (size_t)nb * 128 * HDIM,
               db2, d2c, lds, tid);
    }
  } else if (t < 200) {             // mean/std + nll for step p-3
    if (p >= 3 && p <= 258) {
      ms_tile(t - 192, p - 3, d2p, Wms, mbias, sbias, y, nllp, lds, tid);
    }
  } else if (t < 328) {             // GRU0 -> h0_p
    if (p <= 255) {
      int q = t - 200, mb = q >> 4, nb = q & 15;
      gru_tile<true>(mb, nb,
                     y16 + (size_t)p * BB * YDIM, YDIM, Wg0i + (size_t)nb * 96 * YDIM,
                     hA16p, Wg0h + (size_t)nb * 96 * RDIM,
                     bi0, bh0, hAfp, hAfc, hA16c, lds, tid);
    }
  } else {                          // D1 for step p-1
    if (p >= 1 && p <= 256) {
      int q = t - 328, mb = q >> 3, nb = q & 7;
      dec_tile(mb, nb, hB16p, RDIM, RDIM, Wd1 + (size_t)nb * 128 * RDIM,
               db1, d1c, lds, tid);
    }
  }
}

__global__ void finish_kernel(float* out, const char* ws)
{
  if (threadIdx.x == 0 && blockIdx.x == 0)
    out[0] = *(const float*)(ws + OFF_NLL);
}

extern "C" void kernel_launch(void* const* d_in, const int* in_sizes, int n_in,
                              void* d_out, int out_size, void* d_ws, size_t ws_size,
                              hipStream_t stream) {
  (void)in_sizes; (void)n_in; (void)out_size; (void)ws_size;
  const float* y    = (const float*)d_in[0];
  const float* dw1  = (const float*)d_in[1];
  const float* db1  = (const float*)d_in[2];
  const float* dw2  = (const float*)d_in[3];
  const float* db2  = (const float*)d_in[4];
  const float* mw   = (const float*)d_in[5];
  const float* mbias= (const float*)d_in[6];
  const float* sw   = (const float*)d_in[7];
  const float* sbias= (const float*)d_in[8];
  const float* wih0 = (const float*)d_in[9];
  const float* whh0 = (const float*)d_in[10];
  const float* bih0 = (const float*)d_in[11];
  const float* bhh0 = (const float*)d_in[12];
  const float* wih1 = (const float*)d_in[13];
  const float* whh1 = (const float*)d_in[14];
  const float* bih1 = (const float*)d_in[15];
  const float* bhh1 = (const float*)d_in[16];
  char* ws = (char*)d_ws;
  float* out = (float*)d_out;

  prepack_kernel<<<256, 256, 0, stream>>>(y, dw1, dw2, mw, sw,
                                          wih0, whh0, bih0, bhh0,
                                          wih1, whh1, bih1, bhh1, ws);
  for (int p = 0; p < 259; ++p)
    phase_kernel<<<392, 256, 0, stream>>>(p, y, db1, db2, mbias, sbias, ws);
  finish_kernel<<<1, 1, 0, stream>>>(out, ws);
}